// Round 9
// baseline (338.266 us; speedup 1.0000x reference)
//
#include <hip/hip_runtime.h>
#include <hip/hip_bf16.h>
#include <hip/hip_cooperative_groups.h>

namespace cg = cooperative_groups;

typedef __attribute__((ext_vector_type(8))) short bf16x8;
typedef __attribute__((ext_vector_type(4))) float f32x4;

#define NB   4
#define NN   2048
#define FIN  256
#define FOUT 128
#define NSTEP 32               // 32 steps x 64 j = full row

__device__ __forceinline__ unsigned short f2bf(float f) {
    unsigned int u = __builtin_bit_cast(unsigned int, f);
    u += 0x7fffu + ((u >> 16) & 1u);
    return (unsigned short)(u >> 16);
}

// One cooperative kernel, 512 blocks x 256 thr (2 blocks/CU guaranteed).
// P0: W->WT | P1: Wh,s1,s2 | P2: adj->nibbles | P3: attn+LN+GELU -> out.
__global__ __launch_bounds__(256) void k_fused(
    const float* __restrict__ h, const int* __restrict__ adj,
    const float* __restrict__ W, const float* __restrict__ a,
    const float* __restrict__ gamma, const float* __restrict__ beta,
    float* __restrict__ out,
    unsigned short* __restrict__ WT, unsigned short* __restrict__ WhT,
    float* __restrict__ s1, float* __restrict__ s2,
    unsigned int* __restrict__ nbw)
{
    cg::grid_group grid = cg::this_grid();
    __shared__ union {
        struct { unsigned short hs[16][264]; float s1w[4][16], s2w[4][16]; } p1;
        struct { unsigned char sh[4][512]; } p2;
        struct { unsigned int nibW[16][64]; float s2S[NN];
                 unsigned short Ps[2][16][72]; float ZS[16]; float hS[16][132]; } p3;
    } S;

    int t = threadIdx.x, bi = blockIdx.x;
    int w = t >> 6, l = t & 63, lr = l & 15, lk = l >> 4;

    // ================= phase 0: WT[o][k] bf16 =================
    if (bi < 128) {
        int idx = bi * 256 + t;
        int k = idx & 255, o = idx >> 8;
        WT[idx] = f2bf(W[k * FOUT + o]);
    }
    __threadfence();
    grid.sync();

    // ================= phase 1: Wh = h@W, s1, s2 =================
    {
        int blk = bi, nglob0 = blk * 16, b = nglob0 >> 11;
        const float4* h4 = (const float4*)h + (size_t)blk * 1024;
        #pragma unroll
        for (int i = 0; i < 4; ++i) {
            int idx = i * 256 + t;
            float4 v = h4[idx];
            int row = idx >> 6, c4 = (idx & 63) * 4;
            unsigned int lo = (unsigned int)f2bf(v.x) | ((unsigned int)f2bf(v.y) << 16);
            unsigned int hi = (unsigned int)f2bf(v.z) | ((unsigned int)f2bf(v.w) << 16);
            *(uint2*)&S.p1.hs[row][c4] = make_uint2(lo, hi);
        }
        __syncthreads();

        float a1v[2], a2v[2];
        #pragma unroll
        for (int j = 0; j < 2; ++j) {
            a1v[j] = a[(w * 2 + j) * 16 + lr];
            a2v[j] = a[FOUT + (w * 2 + j) * 16 + lr];
        }
        f32x4 acc[2] = {{0.f,0.f,0.f,0.f},{0.f,0.f,0.f,0.f}};
        #pragma unroll
        for (int kk = 0; kk < 8; ++kk) {
            int k0 = kk * 32;
            bf16x8 af = *(const bf16x8*)&S.p1.hs[lr][k0 + lk * 8];
            #pragma unroll
            for (int j = 0; j < 2; ++j) {
                bf16x8 bfr = *(const bf16x8*)(WT + ((w * 2 + j) * 16 + lr) * 256 + k0 + lk * 8);
                acc[j] = __builtin_amdgcn_mfma_f32_16x16x32_bf16(af, bfr, acc[j], 0, 0, 0);
            }
        }
        int nn0 = (nglob0 & 2047) + lk * 4;
        float v1[4] = {0.f,0.f,0.f,0.f}, v2[4] = {0.f,0.f,0.f,0.f};
        #pragma unroll
        for (int j = 0; j < 2; ++j) {
            float x0 = acc[j][0], x1 = acc[j][1], x2 = acc[j][2], x3 = acc[j][3];
            ushort4 pk;
            pk.x = f2bf(x0); pk.y = f2bf(x1); pk.z = f2bf(x2); pk.w = f2bf(x3);
            *(ushort4*)(WhT + (size_t)(b * FOUT + (w * 2 + j) * 16 + lr) * NN + nn0) = pk;
            v1[0] += x0 * a1v[j]; v1[1] += x1 * a1v[j]; v1[2] += x2 * a1v[j]; v1[3] += x3 * a1v[j];
            v2[0] += x0 * a2v[j]; v2[1] += x1 * a2v[j]; v2[2] += x2 * a2v[j]; v2[3] += x3 * a2v[j];
        }
        #pragma unroll
        for (int m = 1; m < 16; m <<= 1)
            #pragma unroll
            for (int r = 0; r < 4; ++r) {
                v1[r] += __shfl_xor(v1[r], m);
                v2[r] += __shfl_xor(v2[r], m);
            }
        if (lr == 0)
            #pragma unroll
            for (int r = 0; r < 4; ++r) {
                S.p1.s1w[w][lk * 4 + r] = v1[r];
                S.p1.s2w[w][lk * 4 + r] = v2[r];
            }
        __syncthreads();
        if (t < 16) {
            s1[nglob0 + t] = S.p1.s1w[0][t] + S.p1.s1w[1][t] + S.p1.s1w[2][t] + S.p1.s1w[3][t];
            s2[nglob0 + t] = S.p1.s2w[0][t] + S.p1.s2w[1][t] + S.p1.s2w[2][t] + S.p1.s2w[3][t];
        }
    }
    __threadfence();
    grid.sync();

    // ================= phase 2: adj -> packed nibble dwords =================
    // wave g handles rows g, g+2048, g+4096, g+6144 (8192 rows total).
    {
        int g = bi * 4 + w;
        for (int it = 0; it < 4; ++it) {
            size_t row = (size_t)g + (size_t)it * 2048;
            const int4* base = (const int4*)adj + row * 512;
            int4 v[8];
            #pragma unroll
            for (int c = 0; c < 8; ++c) v[c] = base[c * 64 + l];   // 8 KB/wave in flight
            #pragma unroll
            for (int c = 0; c < 8; ++c) {
                unsigned char nb = (unsigned char)((v[c].x > 0) | ((v[c].y > 0) << 1) |
                                                   ((v[c].z > 0) << 2) | ((v[c].w > 0) << 3));
                S.p2.sh[w][c * 64 + l] = nb;
            }
            asm volatile("s_waitcnt lgkmcnt(0)" ::: "memory");
            uint2 u = *(const uint2*)&S.p2.sh[w][l * 8];
            unsigned int lo = (u.x & 0xFu) | ((u.x >> 4) & 0xF0u) |
                              ((u.x >> 8) & 0xF00u) | ((u.x >> 12) & 0xF000u);
            unsigned int hi = (u.y & 0xFu) | ((u.y >> 4) & 0xF0u) |
                              ((u.y >> 8) & 0xF00u) | ((u.y >> 12) & 0xF000u);
            nbw[row * 64 + l] = lo | (hi << 16);
        }
    }
    __threadfence();
    grid.sync();

    // ================= phase 3: attention + LN + GELU =================
    {
        int b = bi >> 7, i0 = (bi & 127) * 16;
        int rowA = t >> 4, kA = (t & 15) * 4;

        // stage nibbles (16 rows x 64 dwords) + full s2 row (8 KB)
        {
            const unsigned int* nb = nbw + ((size_t)(b * NN) + i0) * 64;
            #pragma unroll
            for (int i = 0; i < 4; ++i) {
                int idx = i * 256 + t;
                S.p3.nibW[idx >> 6][idx & 63] = nb[idx];
            }
            const float4* s2g = (const float4*)(s2 + b * NN);
            ((float4*)S.p3.s2S)[t]       = s2g[t];
            ((float4*)S.p3.s2S)[256 + t] = s2g[256 + t];
        }
        float s1r = s1[b * NN + i0 + rowA];

        int obase = w * 32;
        const unsigned short* Bb = WhT + (size_t)(b * FOUT + obase + lr) * NN + lk * 8;

        f32x4 acc0 = {0.f,0.f,0.f,0.f}, acc1 = {0.f,0.f,0.f,0.f};
        float zacc = 0.f;

        // 2-deep B-fragment ring (L2-resident loads)
        bf16x8 rb[2][4];
        #pragma unroll
        for (int s = 0; s < 2; ++s) {
            const unsigned short* Bs = Bb + s * 64;
            rb[s][0] = *(const bf16x8*)(Bs);
            rb[s][1] = *(const bf16x8*)(Bs + 32);
            rb[s][2] = *(const bf16x8*)(Bs + 16 * NN);
            rb[s][3] = *(const bf16x8*)(Bs + 16 * NN + 32);
        }
        __syncthreads();                           // staging visible (one-time drain)

        #pragma unroll
        for (int s = 0; s < NSTEP; ++s) {
            const int slot = s & 1;
            bf16x8 b00 = rb[slot][0], b01 = rb[slot][1], b10 = rb[slot][2], b11 = rb[slot][3];
            if (s + 2 < NSTEP) {                   // refill freed ring slot
                const unsigned short* Bs = Bb + (s + 2) * 64;
                rb[slot][0] = *(const bf16x8*)(Bs);
                rb[slot][1] = *(const bf16x8*)(Bs + 32);
                rb[slot][2] = *(const bf16x8*)(Bs + 16 * NN);
                rb[slot][3] = *(const bf16x8*)(Bs + 16 * NN + 32);
            }

            // ---- phase A: P tile from LDS nibbles + s2 ----
            {
                unsigned int word = S.p3.nibW[rowA][s * 2 + ((t >> 3) & 1)];
                unsigned int nib  = (word >> (4 * (t & 7))) & 0xFu;
                float4 svc = *(const float4*)&S.p3.s2S[s * 64 + kA];
                float ss[4] = {svc.x, svc.y, svc.z, svc.w};
                unsigned short u[4];
                #pragma unroll
                for (int i = 0; i < 4; ++i) {
                    float tt  = s1r + ss[i];
                    float lrl = fmaxf(tt, 0.2f * tt);
                    float pp  = ((nib >> i) & 1u) ? __expf(lrl) : 0.f;
                    zacc += pp;
                    u[i] = f2bf(pp);
                }
                unsigned int lo = (unsigned int)u[0] | ((unsigned int)u[1] << 16);
                unsigned int hi = (unsigned int)u[2] | ((unsigned int)u[3] << 16);
                *(uint2*)&S.p3.Ps[slot][rowA][kA] = make_uint2(lo, hi);
            }
            asm volatile("s_waitcnt lgkmcnt(0)" ::: "memory");
            __builtin_amdgcn_s_barrier();
            __builtin_amdgcn_sched_barrier(0);

            // ---- phase B: 4 MFMAs ----
            const unsigned short* pr = &S.p3.Ps[slot][lr][lk * 8];
            bf16x8 a0 = *(const bf16x8*)pr;
            bf16x8 a1 = *(const bf16x8*)(pr + 32);
            acc0 = __builtin_amdgcn_mfma_f32_16x16x32_bf16(a0, b00, acc0, 0, 0, 0);
            acc0 = __builtin_amdgcn_mfma_f32_16x16x32_bf16(a1, b01, acc0, 0, 0, 0);
            acc1 = __builtin_amdgcn_mfma_f32_16x16x32_bf16(a0, b10, acc1, 0, 0, 0);
            acc1 = __builtin_amdgcn_mfma_f32_16x16x32_bf16(a1, b11, acc1, 0, 0, 0);
        }

        // ---- full Z per row ----
        #pragma unroll
        for (int m = 1; m < 16; m <<= 1) zacc += __shfl_xor(zacc, m);
        if ((t & 15) == 0) S.p3.ZS[rowA] = zacc;
        __syncthreads();

        // ---- divide, stage h' ----
        #pragma unroll
        for (int r = 0; r < 4; ++r) {
            int row = lk * 4 + r;
            float rz = 1.f / S.p3.ZS[row];
            S.p3.hS[row][obase + lr]      = acc0[r] * rz;
            S.p3.hS[row][obase + 16 + lr] = acc1[r] * rz;
        }
        __syncthreads();

        // ---- LayerNorm + exact GELU ----
        int c0 = (t & 15) * 8;
        float x[8];
        *(float4*)&x[0] = *(const float4*)&S.p3.hS[rowA][c0];
        *(float4*)&x[4] = *(const float4*)&S.p3.hS[rowA][c0 + 4];
        float sm = 0.f, sq = 0.f;
        #pragma unroll
        for (int i = 0; i < 8; ++i) { sm += x[i]; sq += x[i] * x[i]; }
        #pragma unroll
        for (int m = 1; m < 16; m <<= 1) {
            sm += __shfl_xor(sm, m);
            sq += __shfl_xor(sq, m);
        }
        float mu  = sm * (1.f / 128.f);
        float var = sq * (1.f / 128.f) - mu * mu;
        float rs  = rsqrtf(var + 1e-5f);
        float4 g0 = *(const float4*)(gamma + c0);
        float4 g1 = *(const float4*)(gamma + c0 + 4);
        float4 e0 = *(const float4*)(beta + c0);
        float4 e1 = *(const float4*)(beta + c0 + 4);
        float gg[8] = {g0.x, g0.y, g0.z, g0.w, g1.x, g1.y, g1.z, g1.w};
        float bb[8] = {e0.x, e0.y, e0.z, e0.w, e1.x, e1.y, e1.z, e1.w};
        float y[8];
        #pragma unroll
        for (int i = 0; i < 8; ++i) {
            float v = (x[i] - mu) * rs * gg[i] + bb[i];
            y[i] = 0.5f * v * (1.f + erff(v * 0.70710678118f));
        }
        float* op = out + (size_t)(b * NN + i0 + rowA) * FOUT + c0;
        *(float4*)op       = make_float4(y[0], y[1], y[2], y[3]);
        *(float4*)(op + 4) = make_float4(y[4], y[5], y[6], y[7]);
    }
}

// ---------------- launcher ----------------
extern "C" void kernel_launch(void* const* d_in, const int* in_sizes, int n_in,
                              void* d_out, int out_size, void* d_ws, size_t ws_size,
                              hipStream_t stream) {
    const float* h     = (const float*)d_in[0];
    const int*   adj   = (const int*)d_in[1];
    const float* W     = (const float*)d_in[2];
    const float* a     = (const float*)d_in[3];
    const float* gamma = (const float*)d_in[4];
    const float* beta  = (const float*)d_in[5];
    float* out = (float*)d_out;

    char* ws = (char*)d_ws;
    unsigned short* WT  = (unsigned short*)ws;                       // 64 KiB
    unsigned short* WhT = (unsigned short*)(ws + 65536);             // 2 MiB
    float* s1 = (float*)(ws + 2162688);                              // 8 KiB
    float* s2 = (float*)(ws + 2195456);                              // 8 KiB
    unsigned int* nbw = (unsigned int*)(ws + 2228224);               // 2 MiB

    void* args[] = {(void*)&h, (void*)&adj, (void*)&W, (void*)&a,
                    (void*)&gamma, (void*)&beta, (void*)&out,
                    (void*)&WT, (void*)&WhT, (void*)&s1, (void*)&s2, (void*)&nbw};
    hipLaunchCooperativeKernel((const void*)k_fused, dim3(512), dim3(256),
                               args, 0, stream);
}

// Round 10
// 50.627 us; speedup vs baseline: 6.6816x; 6.6816x over previous
//
#include <hip/hip_runtime.h>
#include <hip/hip_bf16.h>

typedef __attribute__((ext_vector_type(8))) short bf16x8;
typedef __attribute__((ext_vector_type(4))) float f32x4;

#define NB   4
#define NN   2048
#define FIN  256
#define FOUT 128
#define SPLIT 4
#define JCH  (NN / SPLIT)      // 512 j per wave-task
#define NSTEP (JCH / 64)       // 8 steps of 64 j

__device__ __forceinline__ unsigned short f2bf(float f) {
    unsigned int u = __builtin_bit_cast(unsigned int, f);
    u += 0x7fffu + ((u >> 16) & 1u);
    return (unsigned short)(u >> 16);
}

// ---------------- Kernel 0: WT[o][k] bf16 from W[k][o] f32 ----------------
__global__ __launch_bounds__(256) void k_wt(const float* __restrict__ W,
                                            unsigned short* __restrict__ WT) {
    int idx = blockIdx.x * 256 + threadIdx.x;
    int k = idx & 255, o = idx >> 8;
    WT[idx] = f2bf(W[k * FOUT + o]);
}

// ---------------- Kernel 0b: adj -> packed bit dwords (64 MB -> 2 MB) -----
// One wave per row; 8 independent int4 (16 B/lane) loads; wave-local LDS
// repack; coalesced dword stores. nbw[row][d] bit k = adj[row][d*32+k] > 0.
__global__ __launch_bounds__(256) void k_nib(const int* __restrict__ adj,
                                             unsigned int* __restrict__ nbw) {
    __shared__ unsigned char sh[4][512];
    int t = threadIdx.x, w = t >> 6, l = t & 63;
    size_t wg = (size_t)blockIdx.x * 4 + w;        // 8192 waves = 8192 rows
    const int4* base = (const int4*)adj + wg * 512;
    int4 v[8];
    #pragma unroll
    for (int c = 0; c < 8; ++c) v[c] = base[c * 64 + l];
    #pragma unroll
    for (int c = 0; c < 8; ++c) {
        unsigned char nb = (unsigned char)((v[c].x > 0) | ((v[c].y > 0) << 1) |
                                           ((v[c].z > 0) << 2) | ((v[c].w > 0) << 3));
        sh[w][c * 64 + l] = nb;
    }
    asm volatile("s_waitcnt lgkmcnt(0)" ::: "memory");
    uint2 u = *(const uint2*)&sh[w][l * 8];
    unsigned int lo = (u.x & 0xFu) | ((u.x >> 4) & 0xF0u) |
                      ((u.x >> 8) & 0xF00u) | ((u.x >> 12) & 0xF000u);
    unsigned int hi = (u.y & 0xFu) | ((u.y >> 4) & 0xF0u) |
                      ((u.y >> 8) & 0xF00u) | ((u.y >> 12) & 0xF000u);
    nbw[wg * 64 + l] = lo | (hi << 16);
}

// ---------------- Kernel 1: Wh = h@W; writes B-FRAGMENT-ORDER WhB + s1,s2 -
// WhB layout: [((b*8+ot)*32+S)*2+hh][lane 0..63][8 shorts]; frag lane
// (o15=lane&15, kg=lane>>4) holds Wh[j=S*64+hh*32+kg*8+e][ot*16+o15].
__global__ __launch_bounds__(256) void k_wh(const float* __restrict__ h,
                                            const float* __restrict__ a,
                                            const unsigned short* __restrict__ WT,
                                            unsigned short* __restrict__ WhB,
                                            float* __restrict__ s1,
                                            float* __restrict__ s2) {
    __shared__ unsigned short hs[16][264];
    __shared__ float s1w[4][16], s2w[4][16];
    int t = threadIdx.x, blk = blockIdx.x;
    int nglob0 = blk * 16;
    int b = nglob0 >> 11;

    const float4* h4 = (const float4*)h + (size_t)blk * 1024;
    #pragma unroll
    for (int i = 0; i < 4; ++i) {
        int idx = i * 256 + t;
        float4 v = h4[idx];
        int row = idx >> 6, c4 = (idx & 63) * 4;
        unsigned int lo = (unsigned int)f2bf(v.x) | ((unsigned int)f2bf(v.y) << 16);
        unsigned int hi = (unsigned int)f2bf(v.z) | ((unsigned int)f2bf(v.w) << 16);
        *(uint2*)&hs[row][c4] = make_uint2(lo, hi);
    }
    __syncthreads();

    int w = t >> 6, l = t & 63, lr = l & 15, lk = l >> 4;
    float a1v[2], a2v[2];
    #pragma unroll
    for (int j = 0; j < 2; ++j) {
        a1v[j] = a[(w * 2 + j) * 16 + lr];
        a2v[j] = a[FOUT + (w * 2 + j) * 16 + lr];
    }
    f32x4 acc[2] = {{0.f,0.f,0.f,0.f},{0.f,0.f,0.f,0.f}};

    #pragma unroll
    for (int kk = 0; kk < 8; ++kk) {
        int k0 = kk * 32;
        bf16x8 af = *(const bf16x8*)&hs[lr][k0 + lk * 8];
        #pragma unroll
        for (int j = 0; j < 2; ++j) {
            bf16x8 bfr = *(const bf16x8*)(WT + ((w * 2 + j) * 16 + lr) * 256 + k0 + lk * 8);
            acc[j] = __builtin_amdgcn_mfma_f32_16x16x32_bf16(af, bfr, acc[j], 0, 0, 0);
        }
    }

    // epilogue: swizzled WhB write + s1/s2
    int n0 = nglob0 & 2047;
    int sIdx = n0 >> 6;                            // 64-j step
    int hh   = (n0 >> 5) & 1;                      // 32-j half
    int bklo = (n0 & 31) >> 3;                     // base k-group (0 or 2)
    float v1[4] = {0.f,0.f,0.f,0.f}, v2[4] = {0.f,0.f,0.f,0.f};
    #pragma unroll
    for (int j = 0; j < 2; ++j) {
        int ot = w * 2 + j;
        float x0 = acc[j][0], x1 = acc[j][1], x2 = acc[j][2], x3 = acc[j][3];
        ushort4 pk;
        pk.x = f2bf(x0); pk.y = f2bf(x1); pk.z = f2bf(x2); pk.w = f2bf(x3);
        // acc reg r = Wh[n0 + lk*4 + r][ot*16 + lr]; frag lane = lr + 16*kg
        size_t fragBase = (((size_t)(b * 8 + ot) * 32 + sIdx) * 2 + hh) * 64;
        size_t lane = fragBase + lr + 16 * (bklo + (lk >> 1));
        *(ushort4*)(WhB + lane * 8 + (lk & 1) * 4) = pk;
        v1[0] += x0 * a1v[j]; v1[1] += x1 * a1v[j]; v1[2] += x2 * a1v[j]; v1[3] += x3 * a1v[j];
        v2[0] += x0 * a2v[j]; v2[1] += x1 * a2v[j]; v2[2] += x2 * a2v[j]; v2[3] += x3 * a2v[j];
    }
    #pragma unroll
    for (int m = 1; m < 16; m <<= 1)
        #pragma unroll
        for (int r = 0; r < 4; ++r) {
            v1[r] += __shfl_xor(v1[r], m);
            v2[r] += __shfl_xor(v2[r], m);
        }
    if (lr == 0)
        #pragma unroll
        for (int r = 0; r < 4; ++r) {
            s1w[w][lk * 4 + r] = v1[r];
            s2w[w][lk * 4 + r] = v2[r];
        }
    __syncthreads();
    if (t < 16) {
        s1[nglob0 + t] = s1w[0][t] + s1w[1][t] + s1w[2][t] + s1w[3][t];
        s2[nglob0 + t] = s2w[0][t] + s2w[1][t] + s2w[2][t] + s2w[3][t];
    }
}

// ---------------- Kernel 2: wave-autonomous attention, P in registers -----
// 512 blocks x 256 thr = 2048 wave-tasks (16 i x 512 j x 128 o each).
// NO barriers in loop; no LDS P. Lane (lr,lk) computes the exact 16 exps its
// A-frags need (i=lr, j=s*64+hh*32+lk*8+e). B: one coalesced 1KB load/frag.
__global__ __launch_bounds__(256, 2) void k_attn(const unsigned int* __restrict__ nbw,
                                                 const unsigned short* __restrict__ WhB,
                                                 const float* __restrict__ s1,
                                                 const float* __restrict__ s2,
                                                 float* __restrict__ num,
                                                 float* __restrict__ Zp) {
    __shared__ union {
        struct { unsigned int nib[4][16][17]; float s2c[4][512]; } lp;  // 12.5 KB
        struct { float hS[4][16][132]; } ep;                            // 33 KB
    } S;

    int t = threadIdx.x, w = t >> 6, l = t & 63, lr = l & 15, lk = l >> 4;
    int wid = blockIdx.x * 4 + w;
    int part = wid >> 9, rem = wid & 511;
    int b = rem >> 7, i0 = (rem & 127) * 16;

    // ---- wave-local staging: nib (16x16 dwords) + s2 chunk (512 f) ----
    const unsigned int* nbp = nbw + ((size_t)(b * NN) + i0) * 64 + part * 16;
    #pragma unroll
    for (int q = 0; q < 4; ++q) {
        int idx = q * 64 + l, row = idx >> 4, c = idx & 15;
        S.lp.nib[w][row][c] = nbp[(size_t)row * 64 + c];
    }
    const float4* s2g = (const float4*)(s2 + b * NN + part * JCH);
    ((float4*)S.lp.s2c[w])[l]      = s2g[l];
    ((float4*)S.lp.s2c[w])[64 + l] = s2g[64 + l];
    float s1r = s1[b * NN + i0 + lr];
    asm volatile("s_waitcnt lgkmcnt(0)" ::: "memory");   // wave-local visibility

    f32x4 acc[8];
    #pragma unroll
    for (int ot = 0; ot < 8; ++ot) acc[ot] = (f32x4){0.f, 0.f, 0.f, 0.f};
    float zacc = 0.f;

    #pragma unroll
    for (int s = 0; s < NSTEP; ++s) {
        int Sg = part * NSTEP + s;
        // ---- 16 coalesced B-frag loads (1 KB each, L2-resident) ----
        bf16x8 bfr[8][2];
        #pragma unroll
        for (int ot = 0; ot < 8; ++ot)
            #pragma unroll
            for (int hh = 0; hh < 2; ++hh)
                bfr[ot][hh] = *(const bf16x8*)(WhB +
                    ((((size_t)(b * 8 + ot) * 32 + Sg) * 2 + hh) * 64 + l) * 8);

        // ---- A-frags in registers: 16 exps for (i=lr, own j-slots) ----
        unsigned int wd0 = S.lp.nib[w][lr][s * 2]     >> (lk * 8);
        unsigned int wd1 = S.lp.nib[w][lr][s * 2 + 1] >> (lk * 8);
        bf16x8 pa[2];
        #pragma unroll
        for (int hh = 0; hh < 2; ++hh) {
            const float* sp = &S.lp.s2c[w][s * 64 + hh * 32 + lk * 8];
            float4 f0 = *(const float4*)sp;
            float4 f1 = *(const float4*)(sp + 4);
            float sv[8] = {f0.x, f0.y, f0.z, f0.w, f1.x, f1.y, f1.z, f1.w};
            unsigned int bits = hh ? wd1 : wd0;
            unsigned int pw[4];
            #pragma unroll
            for (int q = 0; q < 4; ++q) {
                float e0 = s1r + sv[2 * q];
                float e1 = s1r + sv[2 * q + 1];
                e0 = fmaxf(e0, 0.2f * e0);
                e1 = fmaxf(e1, 0.2f * e1);
                float p0 = ((bits >> (2 * q))     & 1u) ? __expf(e0) : 0.f;
                float p1 = ((bits >> (2 * q + 1)) & 1u) ? __expf(e1) : 0.f;
                zacc += p0 + p1;
                pw[q] = (unsigned int)f2bf(p0) | ((unsigned int)f2bf(p1) << 16);
            }
            pa[hh] = __builtin_bit_cast(bf16x8, (uint4){pw[0], pw[1], pw[2], pw[3]});
        }

        // ---- 16 MFMAs ----
        #pragma unroll
        for (int ot = 0; ot < 8; ++ot) {
            acc[ot] = __builtin_amdgcn_mfma_f32_16x16x32_bf16(pa[0], bfr[ot][0], acc[ot], 0, 0, 0);
            acc[ot] = __builtin_amdgcn_mfma_f32_16x16x32_bf16(pa[1], bfr[ot][1], acc[ot], 0, 0, 0);
        }
    }

    // ---- Z partial: lane covers i=lr; reduce over lk (lane bits 4,5) ----
    zacc += __shfl_xor(zacc, 16);
    zacc += __shfl_xor(zacc, 32);
    if (l < 16) Zp[(size_t)(part * NB + b) * NN + i0 + l] = zacc;

    // ---- epilogue: acc -> LDS -> coalesced num stores ----
    __syncthreads();                               // lp no longer needed by any wave
    #pragma unroll
    for (int ot = 0; ot < 8; ++ot)
        #pragma unroll
        for (int r = 0; r < 4; ++r)
            S.ep.hS[w][lk * 4 + r][ot * 16 + lr] = acc[ot][r];
    asm volatile("s_waitcnt lgkmcnt(0)" ::: "memory");
    float* np = num + ((size_t)(part * NB + b) * NN + i0) * FOUT;
    #pragma unroll
    for (int q = 0; q < 8; ++q) {
        int idx = q * 256 + l * 4, row = idx >> 7, col = idx & 127;
        *(float4*)(np + (size_t)row * FOUT + col) = *(const float4*)&S.ep.hS[w][row][col];
    }
}

// ---------------- Kernel 3: reduce splits + LayerNorm + GELU --------------
__global__ __launch_bounds__(256) void k_final(const float* __restrict__ num,
                                               const float* __restrict__ Zp,
                                               const float* __restrict__ gamma,
                                               const float* __restrict__ beta,
                                               float* __restrict__ out) {
    int t = threadIdx.x, bi = blockIdx.x;
    int rowA = t >> 5;
    int c0 = (t & 31) * 4;
    size_t gn = (size_t)bi * 8 + rowA;
    int b = (int)(gn >> 11), n = (int)(gn & 2047);

    float Z = 0.f;
    #pragma unroll
    for (int p = 0; p < SPLIT; ++p) Z += Zp[(size_t)(p * NB + b) * NN + n];

    float x[4] = {0.f, 0.f, 0.f, 0.f};
    #pragma unroll
    for (int p = 0; p < SPLIT; ++p) {
        const float* np = num + ((size_t)(p * NB + b) * NN + n) * FOUT + c0;
        float4 v0 = *(const float4*)np;
        x[0] += v0.x; x[1] += v0.y; x[2] += v0.z; x[3] += v0.w;
    }
    float rz = 1.f / Z;
    #pragma unroll
    for (int i = 0; i < 4; ++i) x[i] *= rz;

    float sm = 0.f, sq = 0.f;
    #pragma unroll
    for (int i = 0; i < 4; ++i) { sm += x[i]; sq += x[i] * x[i]; }
    #pragma unroll
    for (int m = 1; m < 32; m <<= 1) {
        sm += __shfl_xor(sm, m);
        sq += __shfl_xor(sq, m);
    }
    float mu  = sm * (1.f / 128.f);
    float var = sq * (1.f / 128.f) - mu * mu;
    float rs  = rsqrtf(var + 1e-5f);
    float4 g0 = *(const float4*)(gamma + c0);
    float4 e0 = *(const float4*)(beta + c0);
    float gg[4] = {g0.x, g0.y, g0.z, g0.w};
    float bb[4] = {e0.x, e0.y, e0.z, e0.w};
    float y[4];
    #pragma unroll
    for (int i = 0; i < 4; ++i) {
        float v = (x[i] - mu) * rs * gg[i] + bb[i];
        y[i] = 0.5f * v * (1.f + erff(v * 0.70710678118f));
    }
    float* op = out + gn * FOUT + c0;
    *(float4*)op = make_float4(y[0], y[1], y[2], y[3]);
}

// ---------------- launcher ----------------
extern "C" void kernel_launch(void* const* d_in, const int* in_sizes, int n_in,
                              void* d_out, int out_size, void* d_ws, size_t ws_size,
                              hipStream_t stream) {
    const float* h     = (const float*)d_in[0];
    const int*   adj   = (const int*)d_in[1];
    const float* W     = (const float*)d_in[2];
    const float* a     = (const float*)d_in[3];
    const float* gamma = (const float*)d_in[4];
    const float* beta  = (const float*)d_in[5];
    float* out = (float*)d_out;

    char* ws = (char*)d_ws;
    unsigned short* WT  = (unsigned short*)ws;                       // 64 KiB
    unsigned short* WhB = (unsigned short*)(ws + (1u << 16));        // 2 MiB
    float* s1 = (float*)(ws + 2162688);                              // 32 KiB
    float* s2 = (float*)(ws + 2195456);                              // 32 KiB
    float* Zp = (float*)(ws + 2228224);                              // 128 KiB
    float* num = (float*)(ws + 2359296);                             // 16 MiB
    unsigned int* nbw = (unsigned int*)(ws + 19136512);              // 2 MiB

    hipLaunchKernelGGL(k_wt,    dim3(128),  dim3(256), 0, stream, W, WT);
    hipLaunchKernelGGL(k_nib,   dim3(2048), dim3(256), 0, stream, adj, nbw);
    hipLaunchKernelGGL(k_wh,    dim3(512),  dim3(256), 0, stream, h, a, WT, WhB, s1, s2);
    hipLaunchKernelGGL(k_attn,  dim3(512),  dim3(256), 0, stream, nbw, WhB, s1, s2, num, Zp);
    hipLaunchKernelGGL(k_final, dim3(1024), dim3(256), 0, stream, num, Zp, gamma, beta, out);
}

// Round 11
// 49.527 us; speedup vs baseline: 6.8299x; 1.0222x over previous
//
#include <hip/hip_runtime.h>
#include <hip/hip_bf16.h>

typedef __attribute__((ext_vector_type(8))) short bf16x8;
typedef __attribute__((ext_vector_type(4))) float f32x4;

#define NB   4
#define NN   2048
#define FIN  256
#define FOUT 128
#define SPLIT 4
#define JCH  (NN / SPLIT)      // 512 j per wave-task
#define NSTEP (JCH / 64)       // 8 steps of 64 j

__device__ __forceinline__ unsigned short f2bf(float f) {
    unsigned int u = __builtin_bit_cast(unsigned int, f);
    u += 0x7fffu + ((u >> 16) & 1u);
    return (unsigned short)(u >> 16);
}

// ---------------- Kernel 0: WT[o][k] bf16 from W[k][o] f32 ----------------
__global__ __launch_bounds__(256) void k_wt(const float* __restrict__ W,
                                            unsigned short* __restrict__ WT) {
    int idx = blockIdx.x * 256 + threadIdx.x;
    int k = idx & 255, o = idx >> 8;
    WT[idx] = f2bf(W[k * FOUT + o]);
}

// ---------------- Kernel 0b: adj -> packed bit dwords (64 MB -> 2 MB) -----
__global__ __launch_bounds__(256) void k_nib(const int* __restrict__ adj,
                                             unsigned int* __restrict__ nbw) {
    __shared__ unsigned char sh[4][512];
    int t = threadIdx.x, w = t >> 6, l = t & 63;
    size_t wg = (size_t)blockIdx.x * 4 + w;        // 8192 waves = 8192 rows
    const int4* base = (const int4*)adj + wg * 512;
    int4 v[8];
    #pragma unroll
    for (int c = 0; c < 8; ++c) v[c] = base[c * 64 + l];
    #pragma unroll
    for (int c = 0; c < 8; ++c) {
        unsigned char nb = (unsigned char)((v[c].x > 0) | ((v[c].y > 0) << 1) |
                                           ((v[c].z > 0) << 2) | ((v[c].w > 0) << 3));
        sh[w][c * 64 + l] = nb;
    }
    asm volatile("s_waitcnt lgkmcnt(0)" ::: "memory");
    uint2 u = *(const uint2*)&sh[w][l * 8];
    unsigned int lo = (u.x & 0xFu) | ((u.x >> 4) & 0xF0u) |
                      ((u.x >> 8) & 0xF00u) | ((u.x >> 12) & 0xF000u);
    unsigned int hi = (u.y & 0xFu) | ((u.y >> 4) & 0xF0u) |
                      ((u.y >> 8) & 0xF00u) | ((u.y >> 12) & 0xF000u);
    nbw[wg * 64 + l] = lo | (hi << 16);
}

// ---------------- Kernel 1: Wh = h@W; writes B-FRAGMENT-ORDER WhB + s1,s2 -
__global__ __launch_bounds__(256) void k_wh(const float* __restrict__ h,
                                            const float* __restrict__ a,
                                            const unsigned short* __restrict__ WT,
                                            unsigned short* __restrict__ WhB,
                                            float* __restrict__ s1,
                                            float* __restrict__ s2) {
    __shared__ unsigned short hs[16][264];
    __shared__ float s1w[4][16], s2w[4][16];
    int t = threadIdx.x, blk = blockIdx.x;
    int nglob0 = blk * 16;
    int b = nglob0 >> 11;

    const float4* h4 = (const float4*)h + (size_t)blk * 1024;
    #pragma unroll
    for (int i = 0; i < 4; ++i) {
        int idx = i * 256 + t;
        float4 v = h4[idx];
        int row = idx >> 6, c4 = (idx & 63) * 4;
        unsigned int lo = (unsigned int)f2bf(v.x) | ((unsigned int)f2bf(v.y) << 16);
        unsigned int hi = (unsigned int)f2bf(v.z) | ((unsigned int)f2bf(v.w) << 16);
        *(uint2*)&hs[row][c4] = make_uint2(lo, hi);
    }
    __syncthreads();

    int w = t >> 6, l = t & 63, lr = l & 15, lk = l >> 4;
    float a1v[2], a2v[2];
    #pragma unroll
    for (int j = 0; j < 2; ++j) {
        a1v[j] = a[(w * 2 + j) * 16 + lr];
        a2v[j] = a[FOUT + (w * 2 + j) * 16 + lr];
    }
    f32x4 acc[2] = {{0.f,0.f,0.f,0.f},{0.f,0.f,0.f,0.f}};

    #pragma unroll
    for (int kk = 0; kk < 8; ++kk) {
        int k0 = kk * 32;
        bf16x8 af = *(const bf16x8*)&hs[lr][k0 + lk * 8];
        #pragma unroll
        for (int j = 0; j < 2; ++j) {
            bf16x8 bfr = *(const bf16x8*)(WT + ((w * 2 + j) * 16 + lr) * 256 + k0 + lk * 8);
            acc[j] = __builtin_amdgcn_mfma_f32_16x16x32_bf16(af, bfr, acc[j], 0, 0, 0);
        }
    }

    int n0 = nglob0 & 2047;
    int sIdx = n0 >> 6;
    int hh   = (n0 >> 5) & 1;
    int bklo = (n0 & 31) >> 3;
    float v1[4] = {0.f,0.f,0.f,0.f}, v2[4] = {0.f,0.f,0.f,0.f};
    #pragma unroll
    for (int j = 0; j < 2; ++j) {
        int ot = w * 2 + j;
        float x0 = acc[j][0], x1 = acc[j][1], x2 = acc[j][2], x3 = acc[j][3];
        ushort4 pk;
        pk.x = f2bf(x0); pk.y = f2bf(x1); pk.z = f2bf(x2); pk.w = f2bf(x3);
        size_t fragBase = (((size_t)(b * 8 + ot) * 32 + sIdx) * 2 + hh) * 64;
        size_t lane = fragBase + lr + 16 * (bklo + (lk >> 1));
        *(ushort4*)(WhB + lane * 8 + (lk & 1) * 4) = pk;
        v1[0] += x0 * a1v[j]; v1[1] += x1 * a1v[j]; v1[2] += x2 * a1v[j]; v1[3] += x3 * a1v[j];
        v2[0] += x0 * a2v[j]; v2[1] += x1 * a2v[j]; v2[2] += x2 * a2v[j]; v2[3] += x3 * a2v[j];
    }
    #pragma unroll
    for (int m = 1; m < 16; m <<= 1)
        #pragma unroll
        for (int r = 0; r < 4; ++r) {
            v1[r] += __shfl_xor(v1[r], m);
            v2[r] += __shfl_xor(v2[r], m);
        }
    if (lr == 0)
        #pragma unroll
        for (int r = 0; r < 4; ++r) {
            s1w[w][lk * 4 + r] = v1[r];
            s2w[w][lk * 4 + r] = v2[r];
        }
    __syncthreads();
    if (t < 16) {
        s1[nglob0 + t] = s1w[0][t] + s1w[1][t] + s1w[2][t] + s1w[3][t];
        s2[nglob0 + t] = s2w[0][t] + s2w[1][t] + s2w[2][t] + s2w[3][t];
    }
}

// ---------------- Kernel 2: wave-autonomous attention, 1-wave blocks ------
// 2048 blocks x 64 thr (1 wave) = 2048 tasks (16 i x 512 j x 128 o).
// R10 loop body unchanged (proven); LDS cut to ~3.2 KB so nothing caps
// blocks/CU; at VGPR~72 -> ~7 waves/SIMD = 28 waves/CU (vs R10's 8).
__global__ __launch_bounds__(64) void k_attn(const unsigned int* __restrict__ nbw,
                                             const unsigned short* __restrict__ WhB,
                                             const float* __restrict__ s1,
                                             const float* __restrict__ s2,
                                             float* __restrict__ num,
                                             float* __restrict__ Zp) {
    __shared__ unsigned int nib[16][17];           // 1.1 KB
    __shared__ float s2c[JCH];                     // 2 KB

    int l = threadIdx.x, lr = l & 15, lk = l >> 4;
    int wid = blockIdx.x;
    int part = wid >> 9, rem = wid & 511;
    int b = rem >> 7, i0 = (rem & 127) * 16;

    // ---- wave-local staging: nib (16x16 dwords) + s2 chunk (512 f) ----
    const unsigned int* nbp = nbw + ((size_t)(b * NN) + i0) * 64 + part * 16;
    #pragma unroll
    for (int q = 0; q < 4; ++q) {
        int idx = q * 64 + l, row = idx >> 4, c = idx & 15;
        nib[row][c] = nbp[(size_t)row * 64 + c];
    }
    const float4* s2g = (const float4*)(s2 + b * NN + part * JCH);
    ((float4*)s2c)[l]      = s2g[l];
    ((float4*)s2c)[64 + l] = s2g[64 + l];
    float s1r = s1[b * NN + i0 + lr];
    asm volatile("s_waitcnt lgkmcnt(0)" ::: "memory");   // wave-local visibility

    f32x4 acc[8];
    #pragma unroll
    for (int ot = 0; ot < 8; ++ot) acc[ot] = (f32x4){0.f, 0.f, 0.f, 0.f};
    float zacc = 0.f;

    #pragma unroll
    for (int s = 0; s < NSTEP; ++s) {
        int Sg = part * NSTEP + s;
        // ---- 16 coalesced B-frag loads (1 KB each, L2-resident) ----
        bf16x8 bfr[8][2];
        #pragma unroll
        for (int ot = 0; ot < 8; ++ot)
            #pragma unroll
            for (int hh = 0; hh < 2; ++hh)
                bfr[ot][hh] = *(const bf16x8*)(WhB +
                    ((((size_t)(b * 8 + ot) * 32 + Sg) * 2 + hh) * 64 + l) * 8);

        // ---- A-frags in registers: 16 exps for (i=lr, own j-slots) ----
        unsigned int wd0 = nib[lr][s * 2]     >> (lk * 8);
        unsigned int wd1 = nib[lr][s * 2 + 1] >> (lk * 8);
        bf16x8 pa[2];
        #pragma unroll
        for (int hh = 0; hh < 2; ++hh) {
            const float* sp = &s2c[s * 64 + hh * 32 + lk * 8];
            float4 f0 = *(const float4*)sp;
            float4 f1 = *(const float4*)(sp + 4);
            float sv[8] = {f0.x, f0.y, f0.z, f0.w, f1.x, f1.y, f1.z, f1.w};
            unsigned int bits = hh ? wd1 : wd0;
            unsigned int pw[4];
            #pragma unroll
            for (int q = 0; q < 4; ++q) {
                float e0 = s1r + sv[2 * q];
                float e1 = s1r + sv[2 * q + 1];
                e0 = fmaxf(e0, 0.2f * e0);
                e1 = fmaxf(e1, 0.2f * e1);
                float p0 = ((bits >> (2 * q))     & 1u) ? __expf(e0) : 0.f;
                float p1 = ((bits >> (2 * q + 1)) & 1u) ? __expf(e1) : 0.f;
                zacc += p0 + p1;
                pw[q] = (unsigned int)f2bf(p0) | ((unsigned int)f2bf(p1) << 16);
            }
            pa[hh] = __builtin_bit_cast(bf16x8, (uint4){pw[0], pw[1], pw[2], pw[3]});
        }

        // ---- 16 MFMAs ----
        #pragma unroll
        for (int ot = 0; ot < 8; ++ot) {
            acc[ot] = __builtin_amdgcn_mfma_f32_16x16x32_bf16(pa[0], bfr[ot][0], acc[ot], 0, 0, 0);
            acc[ot] = __builtin_amdgcn_mfma_f32_16x16x32_bf16(pa[1], bfr[ot][1], acc[ot], 0, 0, 0);
        }
    }

    // ---- Z partial: reduce over lk (lane bits 4,5) ----
    zacc += __shfl_xor(zacc, 16);
    zacc += __shfl_xor(zacc, 32);
    if (l < 16) Zp[(size_t)(part * NB + b) * NN + i0 + l] = zacc;

    // ---- epilogue: direct stores (each inst: 4 rows x 64 B segments) ----
    float* np = num + ((size_t)(part * NB + b) * NN + i0) * FOUT;
    #pragma unroll
    for (int ot = 0; ot < 8; ++ot)
        #pragma unroll
        for (int r = 0; r < 4; ++r)
            np[(size_t)(lk * 4 + r) * FOUT + ot * 16 + lr] = acc[ot][r];
}

// ---------------- Kernel 3: reduce splits + LayerNorm + GELU --------------
__global__ __launch_bounds__(256) void k_final(const float* __restrict__ num,
                                               const float* __restrict__ Zp,
                                               const float* __restrict__ gamma,
                                               const float* __restrict__ beta,
                                               float* __restrict__ out) {
    int t = threadIdx.x, bi = blockIdx.x;
    int rowA = t >> 5;
    int c0 = (t & 31) * 4;
    size_t gn = (size_t)bi * 8 + rowA;
    int b = (int)(gn >> 11), n = (int)(gn & 2047);

    float Z = 0.f;
    #pragma unroll
    for (int p = 0; p < SPLIT; ++p) Z += Zp[(size_t)(p * NB + b) * NN + n];

    float x[4] = {0.f, 0.f, 0.f, 0.f};
    #pragma unroll
    for (int p = 0; p < SPLIT; ++p) {
        const float* np = num + ((size_t)(p * NB + b) * NN + n) * FOUT + c0;
        float4 v0 = *(const float4*)np;
        x[0] += v0.x; x[1] += v0.y; x[2] += v0.z; x[3] += v0.w;
    }
    float rz = 1.f / Z;
    #pragma unroll
    for (int i = 0; i < 4; ++i) x[i] *= rz;

    float sm = 0.f, sq = 0.f;
    #pragma unroll
    for (int i = 0; i < 4; ++i) { sm += x[i]; sq += x[i] * x[i]; }
    #pragma unroll
    for (int m = 1; m < 32; m <<= 1) {
        sm += __shfl_xor(sm, m);
        sq += __shfl_xor(sq, m);
    }
    float mu  = sm * (1.f / 128.f);
    float var = sq * (1.f / 128.f) - mu * mu;
    float rs  = rsqrtf(var + 1e-5f);
    float4 g0 = *(const float4*)(gamma + c0);
    float4 e0 = *(const float4*)(beta + c0);
    float gg[4] = {g0.x, g0.y, g0.z, g0.w};
    float bb[4] = {e0.x, e0.y, e0.z, e0.w};
    float y[4];
    #pragma unroll
    for (int i = 0; i < 4; ++i) {
        float v = (x[i] - mu) * rs * gg[i] + bb[i];
        y[i] = 0.5f * v * (1.f + erff(v * 0.70710678118f));
    }
    float* op = out + gn * FOUT + c0;
    *(float4*)op = make_float4(y[0], y[1], y[2], y[3]);
}

// ---------------- launcher ----------------
extern "C" void kernel_launch(void* const* d_in, const int* in_sizes, int n_in,
                              void* d_out, int out_size, void* d_ws, size_t ws_size,
                              hipStream_t stream) {
    const float* h     = (const float*)d_in[0];
    const int*   adj   = (const int*)d_in[1];
    const float* W     = (const float*)d_in[2];
    const float* a     = (const float*)d_in[3];
    const float* gamma = (const float*)d_in[4];
    const float* beta  = (const float*)d_in[5];
    float* out = (float*)d_out;

    char* ws = (char*)d_ws;
    unsigned short* WT  = (unsigned short*)ws;                       // 64 KiB
    unsigned short* WhB = (unsigned short*)(ws + (1u << 16));        // 2 MiB
    float* s1 = (float*)(ws + 2162688);                              // 32 KiB
    float* s2 = (float*)(ws + 2195456);                              // 32 KiB
    float* Zp = (float*)(ws + 2228224);                              // 128 KiB
    float* num = (float*)(ws + 2359296);                             // 16 MiB
    unsigned int* nbw = (unsigned int*)(ws + 19136512);              // 2 MiB

    hipLaunchKernelGGL(k_wt,    dim3(128),  dim3(256), 0, stream, W, WT);
    hipLaunchKernelGGL(k_nib,   dim3(2048), dim3(256), 0, stream, adj, nbw);
    hipLaunchKernelGGL(k_wh,    dim3(512),  dim3(256), 0, stream, h, a, WT, WhB, s1, s2);
    hipLaunchKernelGGL(k_attn,  dim3(2048), dim3(64),  0, stream, nbw, WhB, s1, s2, num, Zp);
    hipLaunchKernelGGL(k_final, dim3(1024), dim3(256), 0, stream, num, Zp, gamma, beta, out);
}